// Round 1
// baseline (354.781 us; speedup 1.0000x reference)
//
#include <hip/hip_runtime.h>
#include <stdint.h>

#define NFEAT 4096
#define UI_PER_ROW (NFEAT / 4) /* 1024 uint32 per row of packed int8 */

// ---------------------------------------------------------------------------
// Exact emulation of the reference's LUT-based rounded integer sqrt.
// Executed once per row by one thread -> cost irrelevant, exactness matters.
// ---------------------------------------------------------------------------
__device__ __forceinline__ int isqrt_floor(int v) {
    int m = (int)sqrtf((float)v);
    while (m * m > v) --m;
    while ((m + 1) * (m + 1) <= v) ++m;
    return m;
}

__device__ __forceinline__ int sqrt_rounded_ref(int d) {
    if (d <= 0) return 0;
    int msb = 31 - __clz(d);       // bit_length - 1
    int k = msb >> 1;              // d <= 65535 -> k <= 7
    int sh = (7 - k) * 2;
    int dn = d << sh;
    int la = (dn >> 8) & 255;
    int mant = isqrt_floor(la * 256 + 128);   // SQRT_LUT[la]
    int qf = mant >> (7 - k);
    int bnd = qf * qf + qf;
    return (d > bnd) ? (qf + 1) : qf;
}

// ---------------------------------------------------------------------------
// K1: global absmax of x. abs(float) >= 0 so uint-bit compare == float compare.
// ---------------------------------------------------------------------------
__global__ __launch_bounds__(256) void absmax_kernel(const float* __restrict__ x,
                                                     size_t n4,
                                                     unsigned* __restrict__ hdr) {
    size_t i = (size_t)blockIdx.x * blockDim.x + threadIdx.x;
    size_t stride = (size_t)gridDim.x * blockDim.x;
    const float4* x4 = (const float4*)x;
    float m = 0.0f;
    for (size_t idx = i; idx < n4; idx += stride) {
        float4 v = x4[idx];
        m = fmaxf(m, fmaxf(fmaxf(fabsf(v.x), fabsf(v.y)),
                           fmaxf(fabsf(v.z), fabsf(v.w))));
    }
#pragma unroll
    for (int off = 32; off; off >>= 1) m = fmaxf(m, __shfl_down(m, off));
    __shared__ float smax[4];
    int lane = threadIdx.x & 63, w = threadIdx.x >> 6;
    if (lane == 0) smax[w] = m;
    __syncthreads();
    if (threadIdx.x == 0) {
        m = fmaxf(fmaxf(smax[0], smax[1]), fmaxf(smax[2], smax[3]));
        atomicMax(hdr + 0, __float_as_uint(m));
    }
}

// ---------------------------------------------------------------------------
// K2: per-row stats. One block (256 thr) per row; 16 elems/thread.
// Integer Ex/Ex2 sums are exact (4096*127^2 < 2^31). Also packs x_int to int8
// (WQ path) and reduces global absmax(y) for scale_out.
// ---------------------------------------------------------------------------
template <bool WQ>
__global__ __launch_bounds__(256) void rowstat_kernel(
    const float* __restrict__ x, const float* __restrict__ gamma,
    const float* __restrict__ beta, unsigned* __restrict__ hdr,
    float* __restrict__ row_mu, float* __restrict__ row_inv,
    uint32_t* __restrict__ xq8) {
#pragma clang fp contract(off)
    const int row = blockIdx.x;
    const int t = threadIdx.x;
    const float4* xr = (const float4*)(x + (size_t)row * NFEAT);
    const float scale_in = fmaxf(__uint_as_float(hdr[0]) / 127.0f, 1e-8f);

    float xv[16];
#pragma unroll
    for (int g = 0; g < 4; ++g) {
        float4 v = xr[g * 256 + t];
        xv[g * 4 + 0] = v.x; xv[g * 4 + 1] = v.y;
        xv[g * 4 + 2] = v.z; xv[g * 4 + 3] = v.w;
    }
    int xi[16];
    int s1 = 0, s2 = 0;
#pragma unroll
    for (int k = 0; k < 16; ++k) {
        float q = rintf(xv[k] / scale_in);     // IEEE div + round-half-even, as ref
        q = fminf(fmaxf(q, -127.0f), 127.0f);
        int qi = (int)q;
        xi[k] = qi;
        s1 += qi;
        s2 += qi * qi;
    }
    if (WQ) {
#pragma unroll
        for (int g = 0; g < 4; ++g) {
            uint32_t p = (uint32_t)(xi[g * 4 + 0] & 255) |
                         ((uint32_t)(xi[g * 4 + 1] & 255) << 8) |
                         ((uint32_t)(xi[g * 4 + 2] & 255) << 16) |
                         ((uint32_t)(xi[g * 4 + 3] & 255) << 24);
            xq8[(size_t)row * UI_PER_ROW + g * 256 + t] = p;
        }
    }
#pragma unroll
    for (int off = 32; off; off >>= 1) {
        s1 += __shfl_down(s1, off);
        s2 += __shfl_down(s2, off);
    }
    __shared__ int a1[4], a2[4];
    __shared__ float smu, sinv;
    const int lane = t & 63, w = t >> 6;
    if (lane == 0) { a1[w] = s1; a2[w] = s2; }
    __syncthreads();
    if (t == 0) {
        int Exi = a1[0] + a1[1] + a1[2] + a1[3];
        int Ex2i = a2[0] + a2[1] + a2[2] + a2[3];
        float Ex = (float)Exi * scale_in;
        float Ex2 = (float)Ex2i * scale_in * scale_in;
        float mu = Ex / (float)NFEAT;
        float var = fmaxf(Ex2 / (float)NFEAT - mu * mu, 0.0f);
        float vr = fminf(fmaxf(rintf(var), 1.0f), 65535.0f);
        int std_int = sqrt_rounded_ref((int)vr);
        float inv_std = 1.0f / fmaxf((float)std_int, 1e-5f);
        row_mu[row] = mu;
        row_inv[row] = inv_std;
        smu = mu;
        sinv = inv_std;
    }
    __syncthreads();
    const float mu = smu, inv = sinv;
    float ym = 0.0f;
#pragma unroll
    for (int g = 0; g < 4; ++g) {
        float4 gm = ((const float4*)gamma)[g * 256 + t];
        float4 bt = ((const float4*)beta)[g * 256 + t];
        float gv[4] = {gm.x, gm.y, gm.z, gm.w};
        float bv[4] = {bt.x, bt.y, bt.z, bt.w};
#pragma unroll
        for (int j = 0; j < 4; ++j) {
            float xq = (float)xi[g * 4 + j] * scale_in;
            float xn = (xq - mu) * inv;
            float y = xn * gv[j] + bv[j];
            ym = fmaxf(ym, fabsf(y));
        }
    }
#pragma unroll
    for (int off = 32; off; off >>= 1) ym = fmaxf(ym, __shfl_down(ym, off));
    __shared__ float aym[4];
    if (lane == 0) aym[w] = ym;
    __syncthreads();
    if (t == 0) {
        float m = fmaxf(fmaxf(aym[0], aym[1]), fmaxf(aym[2], aym[3]));
        atomicMax(hdr + 1, __float_as_uint(m));
    }
}

// ---------------------------------------------------------------------------
// K3 (int8 path): re-expand packed x_int, recompute y bitwise-identically to
// K2, quantize with scale_out, write fp32 output.
// ---------------------------------------------------------------------------
__global__ __launch_bounds__(256) void quantout_q_kernel(
    const uint32_t* __restrict__ xq8, const float* __restrict__ gamma,
    const float* __restrict__ beta, const unsigned* __restrict__ hdr,
    const float* __restrict__ row_mu, const float* __restrict__ row_inv,
    float* __restrict__ out) {
#pragma clang fp contract(off)
    const int row = blockIdx.x;
    const int t = threadIdx.x;
    const float scale_in = fmaxf(__uint_as_float(hdr[0]) / 127.0f, 1e-8f);
    const float scale_out = fmaxf(__uint_as_float(hdr[1]) / 127.0f, 1e-8f);
    const float mu = row_mu[row], inv = row_inv[row];
    const uint32_t* xr = xq8 + (size_t)row * UI_PER_ROW;
    float4* outr = (float4*)(out + (size_t)row * NFEAT);
#pragma unroll
    for (int g = 0; g < 4; ++g) {
        uint32_t p = xr[g * 256 + t];
        float4 gm = ((const float4*)gamma)[g * 256 + t];
        float4 bt = ((const float4*)beta)[g * 256 + t];
        float gv[4] = {gm.x, gm.y, gm.z, gm.w};
        float bv[4] = {bt.x, bt.y, bt.z, bt.w};
        int xs[4] = {(int)(int8_t)(p & 255), (int)(int8_t)((p >> 8) & 255),
                     (int)(int8_t)((p >> 16) & 255), (int)(int8_t)((p >> 24) & 255)};
        float o[4];
#pragma unroll
        for (int j = 0; j < 4; ++j) {
            float xq = (float)xs[j] * scale_in;
            float xn = (xq - mu) * inv;
            float y = xn * gv[j] + bv[j];
            float q = rintf(y / scale_out);
            q = fminf(fmaxf(q, -127.0f), 127.0f);
            o[j] = q * scale_out;
        }
        outr[g * 256 + t] = make_float4(o[0], o[1], o[2], o[3]);
    }
}

// ---------------------------------------------------------------------------
// K3 fallback (ws too small for int8 buffer): recompute x_int from fp32 x.
// Same IEEE ops as K2 -> identical values.
// ---------------------------------------------------------------------------
__global__ __launch_bounds__(256) void quantout_f_kernel(
    const float* __restrict__ x, const float* __restrict__ gamma,
    const float* __restrict__ beta, const unsigned* __restrict__ hdr,
    const float* __restrict__ row_mu, const float* __restrict__ row_inv,
    float* __restrict__ out) {
#pragma clang fp contract(off)
    const int row = blockIdx.x;
    const int t = threadIdx.x;
    const float scale_in = fmaxf(__uint_as_float(hdr[0]) / 127.0f, 1e-8f);
    const float scale_out = fmaxf(__uint_as_float(hdr[1]) / 127.0f, 1e-8f);
    const float mu = row_mu[row], inv = row_inv[row];
    const float4* xr = (const float4*)(x + (size_t)row * NFEAT);
    float4* outr = (float4*)(out + (size_t)row * NFEAT);
#pragma unroll
    for (int g = 0; g < 4; ++g) {
        float4 v = xr[g * 256 + t];
        float4 gm = ((const float4*)gamma)[g * 256 + t];
        float4 bt = ((const float4*)beta)[g * 256 + t];
        float xv[4] = {v.x, v.y, v.z, v.w};
        float gv[4] = {gm.x, gm.y, gm.z, gm.w};
        float bv[4] = {bt.x, bt.y, bt.z, bt.w};
        float o[4];
#pragma unroll
        for (int j = 0; j < 4; ++j) {
            float q = rintf(xv[j] / scale_in);
            q = fminf(fmaxf(q, -127.0f), 127.0f);
            float xq = q * scale_in;
            float xn = (xq - mu) * inv;
            float y = xn * gv[j] + bv[j];
            float qq = rintf(y / scale_out);
            qq = fminf(fmaxf(qq, -127.0f), 127.0f);
            o[j] = qq * scale_out;
        }
        outr[g * 256 + t] = make_float4(o[0], o[1], o[2], o[3]);
    }
}

extern "C" void kernel_launch(void* const* d_in, const int* in_sizes, int n_in,
                              void* d_out, int out_size, void* d_ws, size_t ws_size,
                              hipStream_t stream) {
    const float* x = (const float*)d_in[0];
    const float* gamma = (const float*)d_in[1];
    const float* beta = (const float*)d_in[2];
    float* out = (float*)d_out;

    const int total = in_sizes[0];
    const int rows = total / NFEAT;

    char* ws = (char*)d_ws;
    unsigned* hdr = (unsigned*)ws;                 // [0]=absmax_x bits, [1]=absmax_y bits
    float* row_mu = (float*)(ws + 256);
    float* row_inv = row_mu + rows;
    size_t xq_off = (256 + (size_t)rows * 8 + 255) & ~(size_t)255;
    uint32_t* xq8 = (uint32_t*)(ws + xq_off);
    const bool use_q = ws_size >= xq_off + (size_t)total + 256;

    // ws is re-poisoned to 0xAA before every call -> zero the atomic header.
    hipMemsetAsync(hdr, 0, 8, stream);

    absmax_kernel<<<2048, 256, 0, stream>>>(x, (size_t)total / 4, hdr);

    if (use_q) {
        rowstat_kernel<true><<<rows, 256, 0, stream>>>(x, gamma, beta, hdr,
                                                       row_mu, row_inv, xq8);
        quantout_q_kernel<<<rows, 256, 0, stream>>>(xq8, gamma, beta, hdr,
                                                    row_mu, row_inv, out);
    } else {
        rowstat_kernel<false><<<rows, 256, 0, stream>>>(x, gamma, beta, hdr,
                                                        row_mu, row_inv, nullptr);
        quantout_f_kernel<<<rows, 256, 0, stream>>>(x, gamma, beta, hdr,
                                                    row_mu, row_inv, out);
    }
}

// Round 2
// 350.705 us; speedup vs baseline: 1.0116x; 1.0116x over previous
//
#include <hip/hip_runtime.h>
#include <stdint.h>

#define NFEAT 4096
#define UI_PER_ROW (NFEAT / 4) /* 1024 uint32 per row of packed int8 */

// ---------------------------------------------------------------------------
// Exact emulation of the reference's LUT-based rounded integer sqrt.
// v <= 65535+128 -> sqrtf is within 1 of floor; branchless fixup is exact.
// ---------------------------------------------------------------------------
__device__ __forceinline__ int isqrt_floor_small(int v) {
    int m = (int)sqrtf((float)v);
    m -= (m * m > v);
    m += ((m + 1) * (m + 1) <= v);
    return m;
}

__device__ __forceinline__ int sqrt_rounded_ref(int d) {
    if (d <= 0) return 0;
    int msb = 31 - __clz(d);       // bit_length - 1
    int k = msb >> 1;              // d <= 65535 -> k <= 7
    int sh = (7 - k) * 2;
    int dn = d << sh;
    int la = (dn >> 8) & 255;
    int mant = isqrt_floor_small(la * 256 + 128);   // SQRT_LUT[la]
    int qf = mant >> (7 - k);
    int bnd = qf * qf + qf;
    return (d > bnd) ? (qf + 1) : qf;
}

// ---------------------------------------------------------------------------
// Correctly-rounded x/s for uniform divisor s, given rs = RN(1/s) (one real
// IEEE division, hoisted). Markstein final correction: q0 = RN(x*rs),
// r = fma(-s,q0,x) (exact residual), q = RN(q0 + r*rs) == RN(x/s).
// 3 VALU ops, no VCC serialization, no transcendental.
// ---------------------------------------------------------------------------
__device__ __forceinline__ float div_rn(float x, float s, float rs) {
    float q0 = x * rs;
    float r  = fmaf(-s, q0, x);
    return fmaf(r, rs, q0);
}

// ---------------------------------------------------------------------------
// K1: global absmax of x. 4 independent float4 loads in flight per iter.
// abs-bits compare as uint == float compare since abs >= 0.
// ---------------------------------------------------------------------------
__global__ __launch_bounds__(256, 4) void absmax_kernel(const float* __restrict__ x,
                                                        int n4,
                                                        unsigned* __restrict__ hdr) {
    const float4* x4 = (const float4*)x;
    int i = blockIdx.x * 256 + threadIdx.x;
    const int stride = gridDim.x * 256;
    float m = 0.0f;
    for (; i + 3 * stride < n4; i += 4 * stride) {
        float4 a = x4[i];
        float4 b = x4[i + stride];
        float4 c = x4[i + 2 * stride];
        float4 d = x4[i + 3 * stride];
        float ma = fmaxf(fmaxf(fabsf(a.x), fabsf(a.y)), fmaxf(fabsf(a.z), fabsf(a.w)));
        float mb = fmaxf(fmaxf(fabsf(b.x), fabsf(b.y)), fmaxf(fabsf(b.z), fabsf(b.w)));
        float mc = fmaxf(fmaxf(fabsf(c.x), fabsf(c.y)), fmaxf(fabsf(c.z), fabsf(c.w)));
        float md = fmaxf(fmaxf(fabsf(d.x), fabsf(d.y)), fmaxf(fabsf(d.z), fabsf(d.w)));
        m = fmaxf(m, fmaxf(fmaxf(ma, mb), fmaxf(mc, md)));
    }
    for (; i < n4; i += stride) {
        float4 a = x4[i];
        m = fmaxf(m, fmaxf(fmaxf(fabsf(a.x), fabsf(a.y)), fmaxf(fabsf(a.z), fabsf(a.w))));
    }
#pragma unroll
    for (int off = 32; off; off >>= 1) m = fmaxf(m, __shfl_down(m, off));
    __shared__ float smax[4];
    int lane = threadIdx.x & 63, w = threadIdx.x >> 6;
    if (lane == 0) smax[w] = m;
    __syncthreads();
    if (threadIdx.x == 0) {
        m = fmaxf(fmaxf(smax[0], smax[1]), fmaxf(smax[2], smax[3]));
        atomicMax(hdr + 0, __float_as_uint(m));
    }
}

// ---------------------------------------------------------------------------
// K2: per-row stats. One block (256 thr) per row; 16 elems/thread.
// All 4 x-loads issued up front (launch_bounds(,4) -> 64 VGPR budget keeps
// them in flight). Integer Ex/Ex2 sums exact (4096*127^2 < 2^31). Packs
// x_int to int8 (WQ) and reduces global absmax(y) for scale_out.
// ---------------------------------------------------------------------------
template <bool WQ>
__global__ __launch_bounds__(256, 4) void rowstat_kernel(
    const float* __restrict__ x, const float* __restrict__ gamma,
    const float* __restrict__ beta, unsigned* __restrict__ hdr,
    float* __restrict__ row_mu, float* __restrict__ row_inv,
    uint32_t* __restrict__ xq8) {
#pragma clang fp contract(off)
    const int row = blockIdx.x;
    const int t = threadIdx.x;
    const float4* xr = (const float4*)(x + (size_t)row * NFEAT);
    float4 v0 = xr[t];
    float4 v1 = xr[256 + t];
    float4 v2 = xr[512 + t];
    float4 v3 = xr[768 + t];
    const float s  = fmaxf(__uint_as_float(hdr[0]) / 127.0f, 1e-8f);
    const float rs = 1.0f / s;   // RN reciprocal (one IEEE div)

    float xv[16] = {v0.x, v0.y, v0.z, v0.w, v1.x, v1.y, v1.z, v1.w,
                    v2.x, v2.y, v2.z, v2.w, v3.x, v3.y, v3.z, v3.w};
    int xi[16];
    int s1 = 0, s2 = 0;
#pragma unroll
    for (int k = 0; k < 16; ++k) {
        float q = rintf(div_rn(xv[k], s, rs));  // == rintf(IEEE x/s)
        q = fminf(fmaxf(q, -127.0f), 127.0f);
        int qi = (int)q;
        xi[k] = qi;
        s1 += qi;
        s2 += qi * qi;
    }
    if (WQ) {
        uint32_t* xw = xq8 + (size_t)row * UI_PER_ROW;
#pragma unroll
        for (int g = 0; g < 4; ++g) {
            uint32_t p = (uint32_t)(xi[4 * g + 0] & 255) |
                         ((uint32_t)(xi[4 * g + 1] & 255) << 8) |
                         ((uint32_t)(xi[4 * g + 2] & 255) << 16) |
                         ((uint32_t)xi[4 * g + 3] << 24);
            xw[g * 256 + t] = p;
        }
    }
#pragma unroll
    for (int off = 32; off; off >>= 1) {
        s1 += __shfl_down(s1, off);
        s2 += __shfl_down(s2, off);
    }
    __shared__ int a1[4], a2[4];
    __shared__ float smu, sinv;
    const int lane = t & 63, w = t >> 6;
    if (lane == 0) { a1[w] = s1; a2[w] = s2; }
    __syncthreads();
    if (t == 0) {
        int Exi = a1[0] + a1[1] + a1[2] + a1[3];
        int Ex2i = a2[0] + a2[1] + a2[2] + a2[3];
        float Ex = (float)Exi * s;
        float Ex2 = (float)Ex2i * s * s;
        float mu = Ex / (float)NFEAT;
        float var = fmaxf(Ex2 / (float)NFEAT - mu * mu, 0.0f);
        float vr = fminf(fmaxf(rintf(var), 1.0f), 65535.0f);
        int std_int = sqrt_rounded_ref((int)vr);
        float inv_std = 1.0f / fmaxf((float)std_int, 1e-5f);
        row_mu[row] = mu;
        row_inv[row] = inv_std;
        smu = mu;
        sinv = inv_std;
    }
    __syncthreads();
    const float mu = smu, inv = sinv;
    float ym = 0.0f;
#pragma unroll
    for (int g = 0; g < 4; ++g) {
        float4 gm = ((const float4*)gamma)[g * 256 + t];
        float4 bt = ((const float4*)beta)[g * 256 + t];
        float gv[4] = {gm.x, gm.y, gm.z, gm.w};
        float bv[4] = {bt.x, bt.y, bt.z, bt.w};
#pragma unroll
        for (int j = 0; j < 4; ++j) {
            float xq = (float)xi[g * 4 + j] * s;
            float xn = (xq - mu) * inv;
            float y = xn * gv[j] + bv[j];   // mul+add (no fma), matches ref path
            ym = fmaxf(ym, fabsf(y));
        }
    }
#pragma unroll
    for (int off = 32; off; off >>= 1) ym = fmaxf(ym, __shfl_down(ym, off));
    __shared__ float aym[4];
    if (lane == 0) aym[w] = ym;
    __syncthreads();
    if (t == 0) {
        float m = fmaxf(fmaxf(aym[0], aym[1]), fmaxf(aym[2], aym[3]));
        atomicMax(hdr + 1, __float_as_uint(m));
    }
}

// ---------------------------------------------------------------------------
// K3 (int8 path): re-expand packed x_int, recompute y bitwise-identically to
// K2 pass 2, quantize with scale_out (Markstein div), write fp32 output.
// Pure stream, no barriers -> should be write-BW-bound.
// ---------------------------------------------------------------------------
__global__ __launch_bounds__(256, 4) void quantout_q_kernel(
    const uint32_t* __restrict__ xq8, const float* __restrict__ gamma,
    const float* __restrict__ beta, const unsigned* __restrict__ hdr,
    const float* __restrict__ row_mu, const float* __restrict__ row_inv,
    float* __restrict__ out) {
#pragma clang fp contract(off)
    const int row = blockIdx.x;
    const int t = threadIdx.x;
    const float s_in  = fmaxf(__uint_as_float(hdr[0]) / 127.0f, 1e-8f);
    const float s_out = fmaxf(__uint_as_float(hdr[1]) / 127.0f, 1e-8f);
    const float rso = 1.0f / s_out;   // RN reciprocal
    const float mu = row_mu[row], inv = row_inv[row];
    const uint32_t* xr = xq8 + (size_t)row * UI_PER_ROW;
    uint32_t p0 = xr[t];
    uint32_t p1 = xr[256 + t];
    uint32_t p2 = xr[512 + t];
    uint32_t p3 = xr[768 + t];
    uint32_t pp[4] = {p0, p1, p2, p3};
    float4* outr = (float4*)(out + (size_t)row * NFEAT);
#pragma unroll
    for (int g = 0; g < 4; ++g) {
        uint32_t p = pp[g];
        float4 gm = ((const float4*)gamma)[g * 256 + t];
        float4 bt = ((const float4*)beta)[g * 256 + t];
        float gv[4] = {gm.x, gm.y, gm.z, gm.w};
        float bv[4] = {bt.x, bt.y, bt.z, bt.w};
        int xs[4] = {(int)(int8_t)(p & 255), (int)(int8_t)((p >> 8) & 255),
                     (int)(int8_t)((p >> 16) & 255), (int)(int8_t)((p >> 24) & 255)};
        float o[4];
#pragma unroll
        for (int j = 0; j < 4; ++j) {
            float xq = (float)xs[j] * s_in;
            float xn = (xq - mu) * inv;
            float y = xn * gv[j] + bv[j];
            float q = rintf(div_rn(y, s_out, rso));
            q = fminf(fmaxf(q, -127.0f), 127.0f);
            o[j] = q * s_out;
        }
        outr[g * 256 + t] = make_float4(o[0], o[1], o[2], o[3]);
    }
}

// ---------------------------------------------------------------------------
// K3 fallback (ws too small for int8 buffer): recompute x_int from fp32 x.
// Same IEEE ops as K2 -> identical values.
// ---------------------------------------------------------------------------
__global__ __launch_bounds__(256, 4) void quantout_f_kernel(
    const float* __restrict__ x, const float* __restrict__ gamma,
    const float* __restrict__ beta, const unsigned* __restrict__ hdr,
    const float* __restrict__ row_mu, const float* __restrict__ row_inv,
    float* __restrict__ out) {
#pragma clang fp contract(off)
    const int row = blockIdx.x;
    const int t = threadIdx.x;
    const float s_in  = fmaxf(__uint_as_float(hdr[0]) / 127.0f, 1e-8f);
    const float s_out = fmaxf(__uint_as_float(hdr[1]) / 127.0f, 1e-8f);
    const float rsi = 1.0f / s_in;
    const float rso = 1.0f / s_out;
    const float mu = row_mu[row], inv = row_inv[row];
    const float4* xr = (const float4*)(x + (size_t)row * NFEAT);
    float4* outr = (float4*)(out + (size_t)row * NFEAT);
#pragma unroll
    for (int g = 0; g < 4; ++g) {
        float4 v = xr[g * 256 + t];
        float4 gm = ((const float4*)gamma)[g * 256 + t];
        float4 bt = ((const float4*)beta)[g * 256 + t];
        float xv[4] = {v.x, v.y, v.z, v.w};
        float gv[4] = {gm.x, gm.y, gm.z, gm.w};
        float bv[4] = {bt.x, bt.y, bt.z, bt.w};
        float o[4];
#pragma unroll
        for (int j = 0; j < 4; ++j) {
            float q = rintf(div_rn(xv[j], s_in, rsi));
            q = fminf(fmaxf(q, -127.0f), 127.0f);
            float xq = q * s_in;
            float xn = (xq - mu) * inv;
            float y = xn * gv[j] + bv[j];
            float qq = rintf(div_rn(y, s_out, rso));
            qq = fminf(fmaxf(qq, -127.0f), 127.0f);
            o[j] = qq * s_out;
        }
        outr[g * 256 + t] = make_float4(o[0], o[1], o[2], o[3]);
    }
}

extern "C" void kernel_launch(void* const* d_in, const int* in_sizes, int n_in,
                              void* d_out, int out_size, void* d_ws, size_t ws_size,
                              hipStream_t stream) {
    const float* x = (const float*)d_in[0];
    const float* gamma = (const float*)d_in[1];
    const float* beta = (const float*)d_in[2];
    float* out = (float*)d_out;

    const int total = in_sizes[0];
    const int rows = total / NFEAT;

    char* ws = (char*)d_ws;
    unsigned* hdr = (unsigned*)ws;                 // [0]=absmax_x bits, [1]=absmax_y bits
    float* row_mu = (float*)(ws + 256);
    float* row_inv = row_mu + rows;
    size_t xq_off = (256 + (size_t)rows * 8 + 255) & ~(size_t)255;
    uint32_t* xq8 = (uint32_t*)(ws + xq_off);
    const bool use_q = ws_size >= xq_off + (size_t)total + 256;

    // ws is re-poisoned to 0xAA before every call -> zero the atomic header.
    hipMemsetAsync(hdr, 0, 8, stream);

    absmax_kernel<<<2048, 256, 0, stream>>>(x, total / 4, hdr);

    if (use_q) {
        rowstat_kernel<true><<<rows, 256, 0, stream>>>(x, gamma, beta, hdr,
                                                       row_mu, row_inv, xq8);
        quantout_q_kernel<<<rows, 256, 0, stream>>>(xq8, gamma, beta, hdr,
                                                    row_mu, row_inv, out);
    } else {
        rowstat_kernel<false><<<rows, 256, 0, stream>>>(x, gamma, beta, hdr,
                                                        row_mu, row_inv, nullptr);
        quantout_f_kernel<<<rows, 256, 0, stream>>>(x, gamma, beta, hdr,
                                                    row_mu, row_inv, out);
    }
}

// Round 5
// 275.307 us; speedup vs baseline: 1.2887x; 1.2739x over previous
//
#include <hip/hip_runtime.h>
#include <stdint.h>

#define NFEAT 4096
#define UI_PER_ROW (NFEAT / 4) /* 1024 uint32 per row of packed int8 */

// 64 atomic slots, each on its own 64-byte line (16 uint32 stride).
#define NSLOT 64
#define SLOT_STRIDE 16

// ---------------------------------------------------------------------------
// Exact emulation of the reference's LUT-based rounded integer sqrt.
// ---------------------------------------------------------------------------
__device__ __forceinline__ int isqrt_floor_small(int v) {
    int m = (int)sqrtf((float)v);
    m -= (m * m > v);
    m += ((m + 1) * (m + 1) <= v);
    return m;
}

__device__ __forceinline__ int sqrt_rounded_ref(int d) {
    if (d <= 0) return 0;
    int msb = 31 - __clz(d);       // bit_length - 1
    int k = msb >> 1;              // d <= 65535 -> k <= 7
    int sh = (7 - k) * 2;
    int dn = d << sh;
    int la = (dn >> 8) & 255;
    int mant = isqrt_floor_small(la * 256 + 128);   // SQRT_LUT[la]
    int qf = mant >> (7 - k);
    int bnd = qf * qf + qf;
    return (d > bnd) ? (qf + 1) : qf;
}

// ---------------------------------------------------------------------------
// Correctly-rounded x/s for uniform divisor s, given rs = RN(1/s).
// Markstein: q0 = RN(x*rs), r = fma(-s,q0,x) exact, q = RN(q0 + r*rs) = RN(x/s).
// ---------------------------------------------------------------------------
__device__ __forceinline__ float div_rn(float x, float s, float rs) {
    float q0 = x * rs;
    float r  = fmaf(-s, q0, x);
    return fmaf(r, rs, q0);
}

// ---------------------------------------------------------------------------
// Per-wave reduce of the 64 atomic slots -> every lane returns the max float.
// Values are abs() bits, so uint compare == float compare. ~64 L2-hot loads.
// ---------------------------------------------------------------------------
__device__ __forceinline__ float slot_max(const unsigned* __restrict__ slots) {
    unsigned v = slots[(threadIdx.x & 63) * SLOT_STRIDE];
#pragma unroll
    for (int off = 32; off; off >>= 1) {
        unsigned o = (unsigned)__shfl_xor((int)v, off);
        v = v > o ? v : o;
    }
    return __uint_as_float(v);
}

// ---------------------------------------------------------------------------
// K1: global absmax of x -> 64 spread atomic slots (one atomic per block).
// ---------------------------------------------------------------------------
__global__ __launch_bounds__(256, 4) void absmax_kernel(const float* __restrict__ x,
                                                        int n4,
                                                        unsigned* __restrict__ hx) {
    const float4* x4 = (const float4*)x;
    int i = blockIdx.x * 256 + threadIdx.x;
    const int stride = gridDim.x * 256;
    float m = 0.0f;
    for (; i + 3 * stride < n4; i += 4 * stride) {
        float4 a = x4[i];
        float4 b = x4[i + stride];
        float4 c = x4[i + 2 * stride];
        float4 d = x4[i + 3 * stride];
        float ma = fmaxf(fmaxf(fabsf(a.x), fabsf(a.y)), fmaxf(fabsf(a.z), fabsf(a.w)));
        float mb = fmaxf(fmaxf(fabsf(b.x), fabsf(b.y)), fmaxf(fabsf(b.z), fabsf(b.w)));
        float mc = fmaxf(fmaxf(fabsf(c.x), fabsf(c.y)), fmaxf(fabsf(c.z), fabsf(c.w)));
        float md = fmaxf(fmaxf(fabsf(d.x), fabsf(d.y)), fmaxf(fabsf(d.z), fabsf(d.w)));
        m = fmaxf(m, fmaxf(fmaxf(ma, mb), fmaxf(mc, md)));
    }
    for (; i < n4; i += stride) {
        float4 a = x4[i];
        m = fmaxf(m, fmaxf(fmaxf(fabsf(a.x), fabsf(a.y)), fmaxf(fabsf(a.z), fabsf(a.w))));
    }
#pragma unroll
    for (int off = 32; off; off >>= 1) m = fmaxf(m, __shfl_down(m, off));
    __shared__ float smax[4];
    int lane = threadIdx.x & 63, w = threadIdx.x >> 6;
    if (lane == 0) smax[w] = m;
    __syncthreads();
    if (threadIdx.x == 0) {
        m = fmaxf(fmaxf(smax[0], smax[1]), fmaxf(smax[2], smax[3]));
        atomicMax(hx + (blockIdx.x & (NSLOT - 1)) * SLOT_STRIDE, __float_as_uint(m));
    }
}

// ---------------------------------------------------------------------------
// K2: per-row stats. One block (256 thr) per row; 16 elems/thread.
// Reads scale_in via slot reduce; ends with ONE spread-slot atomic for y-max.
// ---------------------------------------------------------------------------
template <bool WQ>
__global__ __launch_bounds__(256, 4) void rowstat_kernel(
    const float* __restrict__ x, const float* __restrict__ gamma,
    const float* __restrict__ beta, const unsigned* __restrict__ hx,
    unsigned* __restrict__ hy,
    float* __restrict__ row_mu, float* __restrict__ row_inv,
    uint32_t* __restrict__ xq8) {
#pragma clang fp contract(off)
    const int row = blockIdx.x;
    const int t = threadIdx.x;
    const float4* xr = (const float4*)(x + (size_t)row * NFEAT);
    float4 v0 = xr[t];
    float4 v1 = xr[256 + t];
    float4 v2 = xr[512 + t];
    float4 v3 = xr[768 + t];
    const float s  = fmaxf(slot_max(hx) / 127.0f, 1e-8f);
    const float rs = 1.0f / s;   // RN reciprocal (one IEEE div)

    float xv[16] = {v0.x, v0.y, v0.z, v0.w, v1.x, v1.y, v1.z, v1.w,
                    v2.x, v2.y, v2.z, v2.w, v3.x, v3.y, v3.z, v3.w};
    int xi[16];
    int s1 = 0, s2 = 0;
#pragma unroll
    for (int k = 0; k < 16; ++k) {
        float q = rintf(div_rn(xv[k], s, rs));  // == rintf(IEEE x/s)
        q = fminf(fmaxf(q, -127.0f), 127.0f);
        int qi = (int)q;
        xi[k] = qi;
        s1 += qi;
        s2 += qi * qi;
    }
    if (WQ) {
        uint32_t* xw = xq8 + (size_t)row * UI_PER_ROW;
#pragma unroll
        for (int g = 0; g < 4; ++g) {
            uint32_t p = (uint32_t)(xi[4 * g + 0] & 255) |
                         ((uint32_t)(xi[4 * g + 1] & 255) << 8) |
                         ((uint32_t)(xi[4 * g + 2] & 255) << 16) |
                         ((uint32_t)xi[4 * g + 3] << 24);
            xw[g * 256 + t] = p;
        }
    }
#pragma unroll
    for (int off = 32; off; off >>= 1) {
        s1 += __shfl_down(s1, off);
        s2 += __shfl_down(s2, off);
    }
    __shared__ int a1[4], a2[4];
    __shared__ float smu, sinv;
    const int lane = t & 63, w = t >> 6;
    if (lane == 0) { a1[w] = s1; a2[w] = s2; }
    __syncthreads();
    if (t == 0) {
        int Exi = a1[0] + a1[1] + a1[2] + a1[3];
        int Ex2i = a2[0] + a2[1] + a2[2] + a2[3];
        float Ex = (float)Exi * s;
        float Ex2 = (float)Ex2i * s * s;
        float mu = Ex / (float)NFEAT;
        float var = fmaxf(Ex2 / (float)NFEAT - mu * mu, 0.0f);
        float vr = fminf(fmaxf(rintf(var), 1.0f), 65535.0f);
        int std_int = sqrt_rounded_ref((int)vr);
        float inv_std = 1.0f / fmaxf((float)std_int, 1e-5f);
        row_mu[row] = mu;
        row_inv[row] = inv_std;
        smu = mu;
        sinv = inv_std;
    }
    __syncthreads();
    const float mu = smu, inv = sinv;
    float ym = 0.0f;
#pragma unroll
    for (int g = 0; g < 4; ++g) {
        float4 gm = ((const float4*)gamma)[g * 256 + t];
        float4 bt = ((const float4*)beta)[g * 256 + t];
        float gv[4] = {gm.x, gm.y, gm.z, gm.w};
        float bv[4] = {bt.x, bt.y, bt.z, bt.w};
#pragma unroll
        for (int j = 0; j < 4; ++j) {
            float xq = (float)xi[g * 4 + j] * s;
            float xn = (xq - mu) * inv;
            float y = xn * gv[j] + bv[j];   // mul+add (no fma), matches ref path
            ym = fmaxf(ym, fabsf(y));
        }
    }
#pragma unroll
    for (int off = 32; off; off >>= 1) ym = fmaxf(ym, __shfl_down(ym, off));
    __shared__ float aym[4];
    if (lane == 0) aym[w] = ym;
    __syncthreads();
    if (t == 0) {
        float m = fmaxf(fmaxf(aym[0], aym[1]), fmaxf(aym[2], aym[3]));
        atomicMax(hy + (row & (NSLOT - 1)) * SLOT_STRIDE, __float_as_uint(m));
    }
}

// ---------------------------------------------------------------------------
// K3 (int8 path): re-expand packed x_int, recompute y bitwise-identically to
// K2 pass 2, quantize with scale_out, write fp32 output. No atomics.
// ---------------------------------------------------------------------------
__global__ __launch_bounds__(256, 4) void quantout_q_kernel(
    const uint32_t* __restrict__ xq8, const float* __restrict__ gamma,
    const float* __restrict__ beta, const unsigned* __restrict__ hx,
    const unsigned* __restrict__ hy,
    const float* __restrict__ row_mu, const float* __restrict__ row_inv,
    float* __restrict__ out) {
#pragma clang fp contract(off)
    const int row = blockIdx.x;
    const int t = threadIdx.x;
    const uint32_t* xr = xq8 + (size_t)row * UI_PER_ROW;
    uint32_t p0 = xr[t];
    uint32_t p1 = xr[256 + t];
    uint32_t p2 = xr[512 + t];
    uint32_t p3 = xr[768 + t];
    const float s_in  = fmaxf(slot_max(hx) / 127.0f, 1e-8f);
    const float s_out = fmaxf(slot_max(hy) / 127.0f, 1e-8f);
    const float rso = 1.0f / s_out;   // RN reciprocal
    const float mu = row_mu[row], inv = row_inv[row];
    uint32_t pp[4] = {p0, p1, p2, p3};
    float4* outr = (float4*)(out + (size_t)row * NFEAT);
#pragma unroll
    for (int g = 0; g < 4; ++g) {
        uint32_t p = pp[g];
        float4 gm = ((const float4*)gamma)[g * 256 + t];
        float4 bt = ((const float4*)beta)[g * 256 + t];
        float gv[4] = {gm.x, gm.y, gm.z, gm.w};
        float bv[4] = {bt.x, bt.y, bt.z, bt.w};
        int xs[4] = {(int)(int8_t)(p & 255), (int)(int8_t)((p >> 8) & 255),
                     (int)(int8_t)((p >> 16) & 255), (int)(int8_t)((p >> 24) & 255)};
        float o[4];
#pragma unroll
        for (int j = 0; j < 4; ++j) {
            float xq = (float)xs[j] * s_in;
            float xn = (xq - mu) * inv;
            float y = xn * gv[j] + bv[j];
            float q = rintf(div_rn(y, s_out, rso));
            q = fminf(fmaxf(q, -127.0f), 127.0f);
            o[j] = q * s_out;
        }
        outr[g * 256 + t] = make_float4(o[0], o[1], o[2], o[3]);
    }
}

// ---------------------------------------------------------------------------
// K3 fallback (ws too small for int8 buffer): recompute x_int from fp32 x.
// ---------------------------------------------------------------------------
__global__ __launch_bounds__(256, 4) void quantout_f_kernel(
    const float* __restrict__ x, const float* __restrict__ gamma,
    const float* __restrict__ beta, const unsigned* __restrict__ hx,
    const unsigned* __restrict__ hy,
    const float* __restrict__ row_mu, const float* __restrict__ row_inv,
    float* __restrict__ out) {
#pragma clang fp contract(off)
    const int row = blockIdx.x;
    const int t = threadIdx.x;
    const float4* xr = (const float4*)(x + (size_t)row * NFEAT);
    float4 w0 = xr[t];
    float4 w1 = xr[256 + t];
    float4 w2 = xr[512 + t];
    float4 w3 = xr[768 + t];
    const float s_in  = fmaxf(slot_max(hx) / 127.0f, 1e-8f);
    const float s_out = fmaxf(slot_max(hy) / 127.0f, 1e-8f);
    const float rsi = 1.0f / s_in;
    const float rso = 1.0f / s_out;
    const float mu = row_mu[row], inv = row_inv[row];
    float4 vv[4] = {w0, w1, w2, w3};
    float4* outr = (float4*)(out + (size_t)row * NFEAT);
#pragma unroll
    for (int g = 0; g < 4; ++g) {
        float4 v = vv[g];
        float4 gm = ((const float4*)gamma)[g * 256 + t];
        float4 bt = ((const float4*)beta)[g * 256 + t];
        float xv[4] = {v.x, v.y, v.z, v.w};
        float gv[4] = {gm.x, gm.y, gm.z, gm.w};
        float bv[4] = {bt.x, bt.y, bt.z, bt.w};
        float o[4];
#pragma unroll
        for (int j = 0; j < 4; ++j) {
            float q = rintf(div_rn(xv[j], s_in, rsi));
            q = fminf(fmaxf(q, -127.0f), 127.0f);
            float xq = q * s_in;
            float xn = (xq - mu) * inv;
            float y = xn * gv[j] + bv[j];
            float qq = rintf(div_rn(y, s_out, rso));
            qq = fminf(fmaxf(qq, -127.0f), 127.0f);
            o[j] = qq * s_out;
        }
        outr[g * 256 + t] = make_float4(o[0], o[1], o[2], o[3]);
    }
}

extern "C" void kernel_launch(void* const* d_in, const int* in_sizes, int n_in,
                              void* d_out, int out_size, void* d_ws, size_t ws_size,
                              hipStream_t stream) {
    const float* x = (const float*)d_in[0];
    const float* gamma = (const float*)d_in[1];
    const float* beta = (const float*)d_in[2];
    float* out = (float*)d_out;

    const int total = in_sizes[0];
    const int rows = total / NFEAT;

    char* ws = (char*)d_ws;
    unsigned* hx = (unsigned*)ws;                  // 64 slots * 64B = 4 KB
    unsigned* hy = (unsigned*)(ws + 4096);         // 64 slots * 64B = 4 KB
    float* row_mu = (float*)(ws + 8192);
    float* row_inv = row_mu + rows;
    size_t xq_off = (8192 + (size_t)rows * 8 + 255) & ~(size_t)255;
    uint32_t* xq8 = (uint32_t*)(ws + xq_off);
    const bool use_q = ws_size >= xq_off + (size_t)total + 256;

    // ws is re-poisoned to 0xAA before every call -> zero the atomic slots.
    hipMemsetAsync(ws, 0, 8192, stream);

    absmax_kernel<<<2048, 256, 0, stream>>>(x, total / 4, hx);

    if (use_q) {
        rowstat_kernel<true><<<rows, 256, 0, stream>>>(x, gamma, beta, hx, hy,
                                                       row_mu, row_inv, xq8);
        quantout_q_kernel<<<rows, 256, 0, stream>>>(xq8, gamma, beta, hx, hy,
                                                    row_mu, row_inv, out);
    } else {
        rowstat_kernel<false><<<rows, 256, 0, stream>>>(x, gamma, beta, hx, hy,
                                                        row_mu, row_inv, nullptr);
        quantout_f_kernel<<<rows, 256, 0, stream>>>(x, gamma, beta, hx, hy,
                                                    row_mu, row_inv, out);
    }
}